// Round 5
// baseline (231.572 us; speedup 1.0000x reference)
//
#include <hip/hip_runtime.h>

// N_RNA=20000, N_PROT=5000, D=128, C=4, E=500000
#define DIM 128
#define NCLS 4

typedef _Float16 f16x8 __attribute__((ext_vector_type(8)));
typedef float    f32x4 __attribute__((ext_vector_type(4)));

// LDS slot stride in halves: 260 B = 130 halves = 65 words. 65%32==1 spreads
// the fragment-read banks (slot + 4q + 16t) near-uniformly over 32 banks.
#define SLOT_H 130

// ---------- fp32 -> fp16 conversion into workspace ----------
__global__ __launch_bounds__(256) void cvt_f16_kernel(
    const float* __restrict__ src, _Float16* __restrict__ dst, int n)
{
    int i = (blockIdx.x * blockDim.x + threadIdx.x) * 8;
    const int stride = gridDim.x * blockDim.x * 8;
    for (; i + 7 < n; i += stride) {
        const float4 a = *(const float4*)(src + i);
        const float4 b = *(const float4*)(src + i + 4);
        f16x8 o;
        o[0] = (_Float16)a.x; o[1] = (_Float16)a.y;
        o[2] = (_Float16)a.z; o[3] = (_Float16)a.w;
        o[4] = (_Float16)b.x; o[5] = (_Float16)b.y;
        o[6] = (_Float16)b.z; o[7] = (_Float16)b.w;
        *(f16x8*)(dst + i) = o;
    }
}

// ---------- pipelined MFMA decoder with LDS-staged coalesced gathers ----------
// Task = 16 edges per wave. Global loads: lanes 0..15 read one full 256B row
// contiguously (4 rows per dwordx4 inst). LDS: 32 slots (16 r + 16 p) per wave.
// A-frag: q[m=lane&15][k=quad*8+j]; B-frag: fused weights, classes>=4 zeroed.
// D[row(edge)=quad*4+reg][col(class)=lane&15].
__global__ __launch_bounds__(256) void decoder_mfma_lds_kernel(
    const _Float16* __restrict__ rna,   // [N_RNA, D] f16
    const _Float16* __restrict__ prot,  // [N_PROT, D] f16
    const int*   __restrict__ ridx,
    const int*   __restrict__ pidx,
    const float* __restrict__ wrel,     // [C, D] f32
    const float* __restrict__ wcls,     // [C, C] f32
    float*       __restrict__ out,      // [E, C]
    int nEdges)
{
    __shared__ _Float16 lds_all[4][32 * SLOT_H];   // 4 waves * 8320 B = 33,280 B
    _Float16* lds = lds_all[threadIdx.x >> 6];

    const int lane = threadIdx.x & 63;
    const int m    = lane & 15;       // frag row (edge) / load chunk
    const int quad = lane >> 4;       // frag K-quad / load row-group
    const int wave   = (blockIdx.x * blockDim.x + threadIdx.x) >> 6;
    const int nwaves = (gridDim.x * blockDim.x) >> 6;

    // ---- B fragments: wf_n[d] = sum_c wrel[c,d] * wcls[c,n], n = lane&15 ----
    const float wc0 = (m < NCLS) ? wcls[0 * NCLS + m] : 0.0f;
    const float wc1 = (m < NCLS) ? wcls[1 * NCLS + m] : 0.0f;
    const float wc2 = (m < NCLS) ? wcls[2 * NCLS + m] : 0.0f;
    const float wc3 = (m < NCLS) ? wcls[3 * NCLS + m] : 0.0f;
    f16x8 bfrag[4];
#pragma unroll
    for (int t = 0; t < 4; ++t) {
        const int d0 = t * 32 + quad * 8;
#pragma unroll
        for (int half = 0; half < 2; ++half) {
            const float4 r0 = *(const float4*)(wrel + 0 * DIM + d0 + half * 4);
            const float4 r1 = *(const float4*)(wrel + 1 * DIM + d0 + half * 4);
            const float4 r2 = *(const float4*)(wrel + 2 * DIM + d0 + half * 4);
            const float4 r3 = *(const float4*)(wrel + 3 * DIM + d0 + half * 4);
            bfrag[t][half * 4 + 0] = (_Float16)(wc0 * r0.x + wc1 * r1.x + wc2 * r2.x + wc3 * r3.x);
            bfrag[t][half * 4 + 1] = (_Float16)(wc0 * r0.y + wc1 * r1.y + wc2 * r2.y + wc3 * r3.y);
            bfrag[t][half * 4 + 2] = (_Float16)(wc0 * r0.z + wc1 * r1.z + wc2 * r2.z + wc3 * r3.z);
            bfrag[t][half * 4 + 3] = (_Float16)(wc0 * r0.w + wc1 * r1.w + wc2 * r2.w + wc3 * r3.w);
        }
    }

    const int nTasks = (nEdges + 15) >> 4;
    if (wave >= nTasks) return;

    // ---- pipeline helpers ----
    // idx: lane needs int4 at edge base e0 + 4*quad (16 lanes per quad share it)
    auto idxLoad = [&](int taskT, int4& ri, int4& pi) {
        int b = (taskT << 4) + 4 * quad;
        if (b + 3 >= nEdges) b = nEdges - 4;   // tail clamp (duplicates, stores guarded)
        ri = *(const int4*)(ridx + b);
        pi = *(const int4*)(pidx + b);
    };
    // rows: inst j loads edge-rows {4*quad+j}: lanes 0..15 cover one 256B row
    auto rowIssue = [&](const int4& ri, const int4& pi, uint4* buf) {
        const int er[4] = {ri.x, ri.y, ri.z, ri.w};
        const int ep[4] = {pi.x, pi.y, pi.z, pi.w};
#pragma unroll
        for (int j = 0; j < 4; ++j) {
            buf[j]     = *((const uint4*)(rna  + (size_t)er[j] * DIM) + m);
            buf[4 + j] = *((const uint4*)(prot + (size_t)ep[j] * DIM) + m);
        }
    };
    auto stage = [&](const uint4* buf) {
#pragma unroll
        for (int j = 0; j < 4; ++j) {
            *(uint4*)(lds + (4 * quad + j) * SLOT_H + m * 8)        = buf[j];
            *(uint4*)(lds + (16 + 4 * quad + j) * SLOT_H + m * 8)   = buf[4 + j];
        }
    };
    auto compute = [&](int taskT) {
        f32x4 acc = {0.f, 0.f, 0.f, 0.f};
#pragma unroll
        for (int t = 0; t < 4; ++t) {
            const f16x8 rv = *(const f16x8*)(lds + m * SLOT_H + quad * 8 + t * 32);
            const f16x8 pv = *(const f16x8*)(lds + (16 + m) * SLOT_H + quad * 8 + t * 32);
            acc = __builtin_amdgcn_mfma_f32_16x16x32_f16(rv * pv, bfrag[t], acc, 0, 0, 0);
        }
        const int e0 = taskT << 4;
        if (m < NCLS) {
#pragma unroll
            for (int reg = 0; reg < 4; ++reg) {
                const int ee = e0 + quad * 4 + reg;
                if (ee < nEdges)
                    out[(size_t)ee * NCLS + m] = fmaxf(acc[reg], 0.0f);
            }
        }
    };

    // ---- 2-deep pipeline: rows(n+1) + idx(n+2) in flight during compute(n) ----
    int task  = wave;
    int4 riC, piC;
    idxLoad(task, riC, piC);
    uint4 bufC[8];
    rowIssue(riC, piC, bufC);

    int taskN = task + nwaves;
    bool hasN = taskN < nTasks;
    int4 riN, piN;
    if (hasN) idxLoad(taskN, riN, piN);

    while (true) {
        stage(bufC);                        // waits only bufC's vmcnt group
        uint4 bufN[8];
        if (hasN) rowIssue(riN, piN, bufN); // next task's rows in flight
        const int taskNN = taskN + nwaves;
        if (taskNN < nTasks) idxLoad(taskNN, riC, piC);  // next-next idx in flight
        compute(task);                      // LDS + MFMA + store overlap the loads
        if (!hasN) break;
        task  = taskN;
        taskN = taskNN;
        hasN  = taskN < nTasks;
#pragma unroll
        for (int j = 0; j < 8; ++j) bufC[j] = bufN[j];
        riN = riC; piN = piC;
    }
}

// ---------- fp32 fallback if workspace is too small ----------
__device__ __forceinline__ float reduce4(float b0, float b1, float b2, float b3, int lane)
{
    const bool lo1 = (lane & 1) == 0;
    float k0 = lo1 ? b0 : b2, s0 = lo1 ? b2 : b0;
    float k1 = lo1 ? b1 : b3, s1 = lo1 ? b3 : b1;
    float v0 = k0 + __shfl_xor(s0, 1, 32);
    float v1 = k1 + __shfl_xor(s1, 1, 32);
    const bool lo2 = (lane & 2) == 0;
    float k = lo2 ? v0 : v1, s = lo2 ? v1 : v0;
    float v = k + __shfl_xor(s, 2, 32);
    v += __shfl_xor(v, 4, 32);
    v += __shfl_xor(v, 8, 32);
    v += __shfl_xor(v, 16, 32);
    return v;
}

__global__ __launch_bounds__(256) void decoder_f32_kernel(
    const float* __restrict__ rna, const float* __restrict__ prot,
    const int* __restrict__ ridx, const int* __restrict__ pidx,
    const float* __restrict__ wrel, const float* __restrict__ wcls,
    float* __restrict__ out, int nEdges)
{
    const int lane32 = threadIdx.x & 31;
    const int hw     = (blockIdx.x * blockDim.x + threadIdx.x) >> 5;
    const int nhw    = (gridDim.x * blockDim.x) >> 5;
    const float4 w0 = *(const float4*)(wrel + 0 * DIM + lane32 * 4);
    const float4 w1 = *(const float4*)(wrel + 1 * DIM + lane32 * 4);
    const float4 w2 = *(const float4*)(wrel + 2 * DIM + lane32 * 4);
    const float4 w3 = *(const float4*)(wrel + 3 * DIM + lane32 * 4);
    float wc[16];
#pragma unroll
    for (int i = 0; i < 16; ++i) wc[i] = wcls[i];
    float4 wf[4];
#pragma unroll
    for (int j = 0; j < 4; ++j) {
        wf[j].x = wc[j] * w0.x + wc[4 + j] * w1.x + wc[8 + j] * w2.x + wc[12 + j] * w3.x;
        wf[j].y = wc[j] * w0.y + wc[4 + j] * w1.y + wc[8 + j] * w2.y + wc[12 + j] * w3.y;
        wf[j].z = wc[j] * w0.z + wc[4 + j] * w1.z + wc[8 + j] * w2.z + wc[12 + j] * w3.z;
        wf[j].w = wc[j] * w0.w + wc[4 + j] * w1.w + wc[8 + j] * w2.w + wc[12 + j] * w3.w;
    }
    const int cls   = ((lane32 & 1) << 1) | ((lane32 >> 1) & 1);
    const int lelem = lane32 * 4;
    for (int e = hw; e < nEdges; e += nhw) {
        const float4 r = *(const float4*)(rna  + (size_t)ridx[e] * DIM + lelem);
        const float4 p = *(const float4*)(prot + (size_t)pidx[e] * DIM + lelem);
        float qx = r.x * p.x, qy = r.y * p.y, qz = r.z * p.z, qw = r.w * p.w;
        float b0 = qx * wf[0].x + qy * wf[0].y + qz * wf[0].z + qw * wf[0].w;
        float b1 = qx * wf[1].x + qy * wf[1].y + qz * wf[1].z + qw * wf[1].w;
        float b2 = qx * wf[2].x + qy * wf[2].y + qz * wf[2].z + qw * wf[2].w;
        float b3 = qx * wf[3].x + qy * wf[3].y + qz * wf[3].z + qw * wf[3].w;
        const float v = reduce4(b0, b1, b2, b3, lane32);
        if (lane32 < 4) out[(size_t)e * NCLS + cls] = fmaxf(v, 0.0f);
    }
}

extern "C" void kernel_launch(void* const* d_in, const int* in_sizes, int n_in,
                              void* d_out, int out_size, void* d_ws, size_t ws_size,
                              hipStream_t stream) {
    const float* rna  = (const float*)d_in[0];
    const float* prot = (const float*)d_in[1];
    const int*   ridx = (const int*)d_in[2];
    const int*   pidx = (const int*)d_in[3];
    const float* wrel = (const float*)d_in[4];
    const float* wcls = (const float*)d_in[5];
    float*       out  = (float*)d_out;

    const int nRnaElems  = in_sizes[0];   // 20000*128
    const int nProtElems = in_sizes[1];   // 5000*128
    const int nEdges     = in_sizes[2];   // 500000

    const size_t rnaBytes  = (size_t)nRnaElems * 2;
    const size_t needBytes = rnaBytes + (size_t)nProtElems * 2;

    if (ws_size >= needBytes && nEdges >= 16) {
        _Float16* rnaH  = (_Float16*)d_ws;
        _Float16* protH = (_Float16*)((char*)d_ws + rnaBytes);

        const int blocksR = (nRnaElems / 8 + 255) / 256;
        hipLaunchKernelGGL(cvt_f16_kernel, dim3(blocksR), dim3(256), 0, stream,
                           rna, rnaH, nRnaElems);
        const int blocksP = (nProtElems / 8 + 255) / 256;
        hipLaunchKernelGGL(cvt_f16_kernel, dim3(blocksP), dim3(256), 0, stream,
                           prot, protH, nProtElems);

        // 1024 blocks = 4 blocks/CU (LDS-limited) = fully resident persistent set;
        // 4096 waves, ~7.6 tasks each -> pipeline amortizes its fill.
        hipLaunchKernelGGL(decoder_mfma_lds_kernel, dim3(1024), dim3(256), 0, stream,
                           rnaH, protH, ridx, pidx, wrel, wcls, out, nEdges);
    } else {
        hipLaunchKernelGGL(decoder_f32_kernel, dim3(8192), dim3(256), 0, stream,
                           rna, prot, ridx, pidx, wrel, wcls, out, nEdges);
    }
}

// Round 6
// 130.649 us; speedup vs baseline: 1.7725x; 1.7725x over previous
//
#include <hip/hip_runtime.h>

// N_RNA=20000, N_PROT=5000, D=128, C=4, E=500000
#define DIM 128
#define NCLS 4

typedef _Float16 f16x8 __attribute__((ext_vector_type(8)));
typedef float    f32x4 __attribute__((ext_vector_type(4)));

// LDS slot stride in halves: 260 B = 65 words; 65 % 32 == 1 spreads the
// per-row base bank by +1 per row -> both writes and fragment reads sit at
// the 8-cycle wave64 LDS floor (no super-linear conflicts).
#define SLOT_H 130

// ---------- fp32 -> fp16 conversion into workspace ----------
__global__ __launch_bounds__(256) void cvt_f16_kernel(
    const float* __restrict__ src, _Float16* __restrict__ dst, int n)
{
    int i = (blockIdx.x * blockDim.x + threadIdx.x) * 8;
    const int stride = gridDim.x * blockDim.x * 8;
    for (; i + 7 < n; i += stride) {
        const float4 a = *(const float4*)(src + i);
        const float4 b = *(const float4*)(src + i + 4);
        f16x8 o;
        o[0] = (_Float16)a.x; o[1] = (_Float16)a.y;
        o[2] = (_Float16)a.z; o[3] = (_Float16)a.w;
        o[4] = (_Float16)b.x; o[5] = (_Float16)b.y;
        o[6] = (_Float16)b.z; o[7] = (_Float16)b.w;
        *(f16x8*)(dst + i) = o;
    }
}

// ---------- MFMA decoder: coalesced gather -> per-wave LDS slab ----------
// Task = 16 edges per wave. Each global load inst: lanes 0..15 read one full
// 256B row (chunk m), row-groups q cover 4 rows -> 4 contiguous 256B segments
// per instruction. Fragments come from LDS in exact MFMA A-layout.
// A-frag: q[m=lane&15][k=quad*8+j]; B-frag: fused weights (classes>=4 zero).
// D[row(edge)=quad*4+reg][col(class)=lane&15]  (verified by R4 pass).
__global__ __launch_bounds__(256) void decoder_mfma_lds2_kernel(
    const _Float16* __restrict__ rna,   // [N_RNA, D] f16
    const _Float16* __restrict__ prot,  // [N_PROT, D] f16
    const int*   __restrict__ ridx,
    const int*   __restrict__ pidx,
    const float* __restrict__ wrel,     // [C, D] f32
    const float* __restrict__ wcls,     // [C, C] f32
    float*       __restrict__ out,      // [E, C]
    int nEdges)
{
    __shared__ _Float16 lds_all[4][32 * SLOT_H];   // 4 waves * 8320 B = 33,280 B
    _Float16* const lds = lds_all[threadIdx.x >> 6];

    const int lane = threadIdx.x & 63;
    const int m    = lane & 15;       // fragment row (edge) / load chunk
    const int q    = lane >> 4;       // fragment K-quad / load row-group
    const int wave   = (blockIdx.x * blockDim.x + threadIdx.x) >> 6;
    const int nwaves = (gridDim.x * blockDim.x) >> 6;

    // ---- B fragments: wf_n[d] = sum_c wrel[c,d] * wcls[c,n], n = lane&15 ----
    const float wc0 = (m < NCLS) ? wcls[0 * NCLS + m] : 0.0f;
    const float wc1 = (m < NCLS) ? wcls[1 * NCLS + m] : 0.0f;
    const float wc2 = (m < NCLS) ? wcls[2 * NCLS + m] : 0.0f;
    const float wc3 = (m < NCLS) ? wcls[3 * NCLS + m] : 0.0f;
    f16x8 bfrag[4];
#pragma unroll
    for (int t = 0; t < 4; ++t) {
        const int d0 = t * 32 + q * 8;
#pragma unroll
        for (int half = 0; half < 2; ++half) {
            const float4 r0 = *(const float4*)(wrel + 0 * DIM + d0 + half * 4);
            const float4 r1 = *(const float4*)(wrel + 1 * DIM + d0 + half * 4);
            const float4 r2 = *(const float4*)(wrel + 2 * DIM + d0 + half * 4);
            const float4 r3 = *(const float4*)(wrel + 3 * DIM + d0 + half * 4);
            bfrag[t][half * 4 + 0] = (_Float16)(wc0 * r0.x + wc1 * r1.x + wc2 * r2.x + wc3 * r3.x);
            bfrag[t][half * 4 + 1] = (_Float16)(wc0 * r0.y + wc1 * r1.y + wc2 * r2.y + wc3 * r3.y);
            bfrag[t][half * 4 + 2] = (_Float16)(wc0 * r0.z + wc1 * r1.z + wc2 * r2.z + wc3 * r3.z);
            bfrag[t][half * 4 + 3] = (_Float16)(wc0 * r0.w + wc1 * r1.w + wc2 * r2.w + wc3 * r3.w);
        }
    }

    const int nTasks = (nEdges + 15) >> 4;

    for (int task = wave; task < nTasks; task += nwaves) {
        // Indices: this lane loads chunk m of the 4 rows in its row-group q.
        int eb = (task << 4) + 4 * q;
        if (eb + 3 >= nEdges) eb = nEdges - 4;   // tail clamp; stores are guarded
        const int4 ri = *(const int4*)(ridx + eb);
        const int4 pi = *(const int4*)(pidx + eb);

        // 8 coalesced row loads — named registers only (no arrays -> no scratch)
        const uint4 r0 = *((const uint4*)(rna  + (size_t)ri.x * DIM) + m);
        const uint4 r1 = *((const uint4*)(rna  + (size_t)ri.y * DIM) + m);
        const uint4 r2 = *((const uint4*)(rna  + (size_t)ri.z * DIM) + m);
        const uint4 r3 = *((const uint4*)(rna  + (size_t)ri.w * DIM) + m);
        const uint4 p0 = *((const uint4*)(prot + (size_t)pi.x * DIM) + m);
        const uint4 p1 = *((const uint4*)(prot + (size_t)pi.y * DIM) + m);
        const uint4 p2 = *((const uint4*)(prot + (size_t)pi.z * DIM) + m);
        const uint4 p3 = *((const uint4*)(prot + (size_t)pi.w * DIM) + m);

        // Stage into the per-wave slab (row 4q+j, chunk m)
        _Float16* const wr = lds + (4 * q) * SLOT_H + m * 8;
        *(uint4*)(wr + 0 * SLOT_H) = r0;
        *(uint4*)(wr + 1 * SLOT_H) = r1;
        *(uint4*)(wr + 2 * SLOT_H) = r2;
        *(uint4*)(wr + 3 * SLOT_H) = r3;
        _Float16* const wp = wr + 16 * SLOT_H;
        *(uint4*)(wp + 0 * SLOT_H) = p0;
        *(uint4*)(wp + 1 * SLOT_H) = p1;
        *(uint4*)(wp + 2 * SLOT_H) = p2;
        *(uint4*)(wp + 3 * SLOT_H) = p3;

        // Fragments in MFMA A-layout (compiler inserts lgkmcnt between
        // the ds_writes above and these reads — same-wave slab, no barrier)
        const _Float16* const rr = lds + m * SLOT_H + q * 8;
        const _Float16* const pr = rr + 16 * SLOT_H;
        f32x4 acc = {0.f, 0.f, 0.f, 0.f};
#pragma unroll
        for (int t = 0; t < 4; ++t) {
            const f16x8 rv = *(const f16x8*)(rr + t * 32);
            const f16x8 pv = *(const f16x8*)(pr + t * 32);
            acc = __builtin_amdgcn_mfma_f32_16x16x32_f16(rv * pv, bfrag[t], acc, 0, 0, 0);
        }

        const int e0 = task << 4;
        if (m < NCLS) {
#pragma unroll
            for (int reg = 0; reg < 4; ++reg) {
                const int ee = e0 + q * 4 + reg;
                if (ee < nEdges)
                    out[(size_t)ee * NCLS + m] = fmaxf(acc[reg], 0.0f);
            }
        }
    }
}

// ---------- fp32 fallback if workspace is too small ----------
__device__ __forceinline__ float reduce4(float b0, float b1, float b2, float b3, int lane)
{
    const bool lo1 = (lane & 1) == 0;
    float k0 = lo1 ? b0 : b2, s0 = lo1 ? b2 : b0;
    float k1 = lo1 ? b1 : b3, s1 = lo1 ? b3 : b1;
    float v0 = k0 + __shfl_xor(s0, 1, 32);
    float v1 = k1 + __shfl_xor(s1, 1, 32);
    const bool lo2 = (lane & 2) == 0;
    float k = lo2 ? v0 : v1, s = lo2 ? v1 : v0;
    float v = k + __shfl_xor(s, 2, 32);
    v += __shfl_xor(v, 4, 32);
    v += __shfl_xor(v, 8, 32);
    v += __shfl_xor(v, 16, 32);
    return v;
}

__global__ __launch_bounds__(256) void decoder_f32_kernel(
    const float* __restrict__ rna, const float* __restrict__ prot,
    const int* __restrict__ ridx, const int* __restrict__ pidx,
    const float* __restrict__ wrel, const float* __restrict__ wcls,
    float* __restrict__ out, int nEdges)
{
    const int lane32 = threadIdx.x & 31;
    const int hw     = (blockIdx.x * blockDim.x + threadIdx.x) >> 5;
    const int nhw    = (gridDim.x * blockDim.x) >> 5;
    const float4 w0 = *(const float4*)(wrel + 0 * DIM + lane32 * 4);
    const float4 w1 = *(const float4*)(wrel + 1 * DIM + lane32 * 4);
    const float4 w2 = *(const float4*)(wrel + 2 * DIM + lane32 * 4);
    const float4 w3 = *(const float4*)(wrel + 3 * DIM + lane32 * 4);
    float wc[16];
#pragma unroll
    for (int i = 0; i < 16; ++i) wc[i] = wcls[i];
    float4 wf[4];
#pragma unroll
    for (int j = 0; j < 4; ++j) {
        wf[j].x = wc[j] * w0.x + wc[4 + j] * w1.x + wc[8 + j] * w2.x + wc[12 + j] * w3.x;
        wf[j].y = wc[j] * w0.y + wc[4 + j] * w1.y + wc[8 + j] * w2.y + wc[12 + j] * w3.y;
        wf[j].z = wc[j] * w0.z + wc[4 + j] * w1.z + wc[8 + j] * w2.z + wc[12 + j] * w3.z;
        wf[j].w = wc[j] * w0.w + wc[4 + j] * w1.w + wc[8 + j] * w2.w + wc[12 + j] * w3.w;
    }
    const int cls   = ((lane32 & 1) << 1) | ((lane32 >> 1) & 1);
    const int lelem = lane32 * 4;
    for (int e = hw; e < nEdges; e += nhw) {
        const float4 r = *(const float4*)(rna  + (size_t)ridx[e] * DIM + lelem);
        const float4 p = *(const float4*)(prot + (size_t)pidx[e] * DIM + lelem);
        float qx = r.x * p.x, qy = r.y * p.y, qz = r.z * p.z, qw = r.w * p.w;
        float b0 = qx * wf[0].x + qy * wf[0].y + qz * wf[0].z + qw * wf[0].w;
        float b1 = qx * wf[1].x + qy * wf[1].y + qz * wf[1].z + qw * wf[1].w;
        float b2 = qx * wf[2].x + qy * wf[2].y + qz * wf[2].z + qw * wf[2].w;
        float b3 = qx * wf[3].x + qy * wf[3].y + qz * wf[3].z + qw * wf[3].w;
        const float v = reduce4(b0, b1, b2, b3, lane32);
        if (lane32 < 4) out[(size_t)e * NCLS + cls] = fmaxf(v, 0.0f);
    }
}

extern "C" void kernel_launch(void* const* d_in, const int* in_sizes, int n_in,
                              void* d_out, int out_size, void* d_ws, size_t ws_size,
                              hipStream_t stream) {
    const float* rna  = (const float*)d_in[0];
    const float* prot = (const float*)d_in[1];
    const int*   ridx = (const int*)d_in[2];
    const int*   pidx = (const int*)d_in[3];
    const float* wrel = (const float*)d_in[4];
    const float* wcls = (const float*)d_in[5];
    float*       out  = (float*)d_out;

    const int nRnaElems  = in_sizes[0];   // 20000*128
    const int nProtElems = in_sizes[1];   // 5000*128
    const int nEdges     = in_sizes[2];   // 500000

    const size_t rnaBytes  = (size_t)nRnaElems * 2;
    const size_t needBytes = rnaBytes + (size_t)nProtElems * 2;

    if (ws_size >= needBytes && nEdges >= 16) {
        _Float16* rnaH  = (_Float16*)d_ws;
        _Float16* protH = (_Float16*)((char*)d_ws + rnaBytes);

        const int blocksR = (nRnaElems / 8 + 255) / 256;
        hipLaunchKernelGGL(cvt_f16_kernel, dim3(blocksR), dim3(256), 0, stream,
                           rna, rnaH, nRnaElems);
        const int blocksP = (nProtElems / 8 + 255) / 256;
        hipLaunchKernelGGL(cvt_f16_kernel, dim3(blocksP), dim3(256), 0, stream,
                           prot, protH, nProtElems);

        // 1024 blocks = 4 blocks/CU (LDS-limited), fully resident; 4096 waves,
        // ~7.6 tasks each. TLP (16 waves/CU) hides gather latency.
        hipLaunchKernelGGL(decoder_mfma_lds2_kernel, dim3(1024), dim3(256), 0, stream,
                           rnaH, protH, ridx, pidx, wrel, wcls, out, nEdges);
    } else {
        hipLaunchKernelGGL(decoder_f32_kernel, dim3(8192), dim3(256), 0, stream,
                           rna, prot, ridx, pidx, wrel, wcls, out, nEdges);
    }
}